// Round 18
// baseline (273.415 us; speedup 1.0000x reference)
//
#include <hip/hip_runtime.h>

// ---------------------------------------------------------------------------
// BipartiteLayer: xp = x@W_in+b ; s = exp(-|[xp_i[s],xp_m[e]]@W_score+b|) ;
// scatter mean/max of xp_pair*s ; h = relu([x,xp,mean,max]@W_out+b)
//
// R18: kill the sv (edge score) arrays. k_fill's 68.5MB WRITE was scattered
// 4B writes x4 arrays dirtying 64B lines each. Score is recomputable in
// k_agg from node scalars: s = exp(-|(a_own[node]+a_oth[col])+b|) --
// bit-identical association; a arrays are L1/L2-resident (200KB).
// k_fill now writes only col_i/col_m -> scattered lines halved.
// gemm_out keeps R17's counted-vmcnt pipeline (neutral but passing).
// ---------------------------------------------------------------------------

typedef __attribute__((ext_vector_type(8))) short bf16x8;   // 8 bf16 = 4 VGPR
typedef __attribute__((ext_vector_type(4))) float f32x4;

static __device__ __forceinline__ unsigned short f2bf(float f) {
  unsigned int u = __float_as_uint(f);
  u = (u + 0x7FFFu + ((u >> 16) & 1u)) >> 16;   // RNE
  return (unsigned short)u;
}
static __device__ __forceinline__ float bf2f(unsigned short s) {
  return __uint_as_float(((unsigned int)s) << 16);
}

#define GLD16(gp, lp)                                                        \
  __builtin_amdgcn_global_load_lds(                                          \
      (const __attribute__((address_space(1))) void*)(gp),                   \
      (__attribute__((address_space(3))) void*)(lp), 16, 0, 0)

// ---- transpose W (KxNcol f32) -> Wt[col][k] bf16 ---------------------------
__global__ void k_prep_wt(const float* __restrict__ Wo,
                          unsigned short* __restrict__ Wt, int K, int Ncol) {
  int idx = blockIdx.x * blockDim.x + threadIdx.x;
  if (idx >= K * Ncol) return;
  int k = idx / Ncol, c = idx % Ncol;
  Wt[(size_t)c * K + k] = f2bf(Wo[idx]);
}

// ---- input GEMM (MFMA): [N,128]f32 @ [128,256] -> xp bf16, a=xp.Ws --------
__global__ __launch_bounds__(256) void k_gemm_in(
    const float* __restrict__ x, const unsigned short* __restrict__ Wint,
    const float* __restrict__ bias, const float* __restrict__ Wsc,
    unsigned short* __restrict__ xp, float* __restrict__ a_out, int N) {
  __shared__ __align__(16) unsigned short Ab[64 * 16 * 8];    // 16 KB
  __shared__ __align__(16) unsigned short Bb[256 * 16 * 8];   // 64 KB
  const int tid = threadIdx.x;
  const int l = tid & 63;
  const int lr = l & 15, lg = l >> 4;
  const int w = tid >> 6, wr = w >> 1, wc = w & 1;
  const int r0 = blockIdx.x * 64;
  const int wbase = tid & 192;                  // w*64, wave-uniform

#pragma unroll
  for (int i = 0; i < 16; ++i) {                // B: 256 rows x 16 chunks
    int g = i * 256 + tid;
    int row = g >> 4, c = g & 15;
    int sc = c ^ (row & 7);
    GLD16(Wint + (size_t)row * 128 + sc * 8,
          &Bb[(size_t)(i * 256 + wbase) * 8]);
  }
#pragma unroll
  for (int i = 0; i < 4; ++i) {                 // A: reg-stage f32->bf16
    int g = i * 256 + tid;
    int row = g >> 4, c = g & 15;
    int ar = min(r0 + row, N - 1);
    const float* src = x + (size_t)ar * 128 + c * 8;
    float4 u = *(const float4*)src;
    float4 v = *(const float4*)(src + 4);
    bf16x8 h;
    h[0] = (short)f2bf(u.x); h[1] = (short)f2bf(u.y);
    h[2] = (short)f2bf(u.z); h[3] = (short)f2bf(u.w);
    h[4] = (short)f2bf(v.x); h[5] = (short)f2bf(v.y);
    h[6] = (short)f2bf(v.z); h[7] = (short)f2bf(v.w);
    *(bf16x8*)&Ab[(size_t)(row * 16 + (c ^ (row & 7))) * 8] = h;
  }
  __syncthreads();

  f32x4 acc[2][8];
#pragma unroll
  for (int m = 0; m < 2; ++m)
#pragma unroll
    for (int t = 0; t < 8; ++t) {
      f32x4 z = {0.f, 0.f, 0.f, 0.f};
      acc[m][t] = z;
    }
#pragma unroll
  for (int kk = 0; kk < 4; ++kk) {
    int chq = kk * 4 + lg;
    bf16x8 a[2], bt[8];
#pragma unroll
    for (int m = 0; m < 2; ++m) {
      int row = wr * 32 + m * 16 + lr;
      a[m] = *(const bf16x8*)&Ab[(row * 16 + (chq ^ (row & 7))) * 8];
    }
#pragma unroll
    for (int t = 0; t < 8; ++t) {
      int row = wc * 128 + t * 16 + lr;
      bt[t] = *(const bf16x8*)&Bb[(row * 16 + (chq ^ (row & 7))) * 8];
    }
#pragma unroll
    for (int m = 0; m < 2; ++m)
#pragma unroll
      for (int t = 0; t < 8; ++t)
        acc[m][t] = __builtin_amdgcn_mfma_f32_16x16x32_bf16(
            a[m], bt[t], acc[m][t], 0, 0, 0);
  }

  float wscv[8], bb[8];
#pragma unroll
  for (int t = 0; t < 8; ++t) {
    int c = wc * 128 + t * 16 + lr;
    wscv[t] = Wsc[c];
    bb[t] = bias[c];
  }
#pragma unroll
  for (int m = 0; m < 2; ++m) {
    int rb = r0 + wr * 32 + m * 16 + lg * 4;    // C/D: col=lane&15, row=lg*4+reg
    float p0 = 0.f, p1 = 0.f, p2 = 0.f, p3 = 0.f;
#pragma unroll
    for (int t = 0; t < 8; ++t) {
      int c = wc * 128 + t * 16 + lr;
      float v0 = acc[m][t][0] + bb[t];
      float v1 = acc[m][t][1] + bb[t];
      float v2 = acc[m][t][2] + bb[t];
      float v3 = acc[m][t][3] + bb[t];
      if (rb + 0 < N) xp[(size_t)(rb + 0) * 256 + c] = f2bf(v0);
      if (rb + 1 < N) xp[(size_t)(rb + 1) * 256 + c] = f2bf(v1);
      if (rb + 2 < N) xp[(size_t)(rb + 2) * 256 + c] = f2bf(v2);
      if (rb + 3 < N) xp[(size_t)(rb + 3) * 256 + c] = f2bf(v3);
      p0 = fmaf(v0, wscv[t], p0); p1 = fmaf(v1, wscv[t], p1);
      p2 = fmaf(v2, wscv[t], p2); p3 = fmaf(v3, wscv[t], p3);
    }
#pragma unroll
    for (int off = 1; off < 16; off <<= 1) {
      p0 += __shfl_xor(p0, off); p1 += __shfl_xor(p1, off);
      p2 += __shfl_xor(p2, off); p3 += __shfl_xor(p3, off);
    }
    if (lr == 0) {
      if (rb + 0 < N) atomicAdd(a_out + rb + 0, p0);
      if (rb + 1 < N) atomicAdd(a_out + rb + 1, p1);
      if (rb + 2 < N) atomicAdd(a_out + rb + 2, p2);
      if (rb + 3 < N) atomicAdd(a_out + rb + 3, p3);
    }
  }
}

// ---- CSR build: degree histogram ------------------------------------------
__global__ void k_deg(const int* __restrict__ es, const int* __restrict__ ee,
                      int E, int* __restrict__ deg_i, int* __restrict__ deg_m) {
  int e = blockIdx.x * blockDim.x + threadIdx.x;
  if (e >= E) return;
  atomicAdd(deg_i + es[e], 1);
  atomicAdd(deg_m + ee[e], 1);
}

// ---- CSR scan phase 1 ------------------------------------------------------
__global__ __launch_bounds__(256) void k_scan_blk(
    const int* __restrict__ deg, int* __restrict__ blksum, int n) {
  __shared__ int sm[256];
  int t = threadIdx.x;
  int i = blockIdx.x * 256 + t;
  sm[t] = (i < n) ? deg[i] : 0;
  __syncthreads();
#pragma unroll
  for (int off = 128; off; off >>= 1) {
    if (t < off) sm[t] += sm[t + off];
    __syncthreads();
  }
  if (t == 0) blksum[blockIdx.x] = sm[0];
}

// ---- CSR scan phase 2 ------------------------------------------------------
__global__ __launch_bounds__(1024) void k_scan_top(
    const int* __restrict__ bs_i, int* __restrict__ bb_i, int nbi,
    const int* __restrict__ bs_m, int* __restrict__ bb_m, int nbm) {
  const int* bs = blockIdx.x ? bs_m : bs_i;
  int* bb = blockIdx.x ? bb_m : bb_i;
  int nb = blockIdx.x ? nbm : nbi;
  __shared__ int sm[1024];
  int t = threadIdx.x;
  int d = (t < nb) ? bs[t] : 0;
  sm[t] = d;
  __syncthreads();
  for (int off = 1; off < 1024; off <<= 1) {    // Hillis-Steele inclusive
    int v = (t >= off) ? sm[t - off] : 0;
    __syncthreads();
    sm[t] += v;
    __syncthreads();
  }
  if (t < nb) bb[t] = sm[t] - d;                // exclusive
}

// ---- CSR scan phase 3 ------------------------------------------------------
__global__ __launch_bounds__(256) void k_scan_wr(
    const int* __restrict__ deg, const int* __restrict__ blkbase,
    int* __restrict__ rp, int* __restrict__ cur, int n, int E) {
  __shared__ int sm[256];
  int t = threadIdx.x;
  int i = blockIdx.x * 256 + t;
  int d = (i < n) ? deg[i] : 0;
  sm[t] = d;
  __syncthreads();
  for (int off = 1; off < 256; off <<= 1) {     // Hillis-Steele inclusive
    int v = (t >= off) ? sm[t - off] : 0;
    __syncthreads();
    sm[t] += v;
    __syncthreads();
  }
  if (i < n) {
    int v = blkbase[blockIdx.x] + sm[t] - d;    // exclusive + block base
    rp[i] = v; cur[i] = v;
  }
  if (i == 0) rp[n] = E;
}

// ---- CSR build: fill (col only; scores recomputed in k_agg) ----------------
__global__ void k_fill(const int* __restrict__ es, const int* __restrict__ ee,
                       int E, int* __restrict__ cur_i, int* __restrict__ col_i,
                       int* __restrict__ cur_m, int* __restrict__ col_m) {
  int e = blockIdx.x * blockDim.x + threadIdx.x;
  if (e >= E) return;
  int s = es[e], m = ee[e];
  int pi = atomicAdd(cur_i + s, 1);
  col_i[pi] = m;
  int pm = atomicAdd(cur_m + m, 1);
  col_m[pm] = s;
}

// ---- wave-per-node CSR aggregation -> Hg (512 gathered cols) + scal --------
// Score recomputed per edge: s = exp(-|(a_own[node] + a_oth[o]) + b|)
// (same FP association as old k_fill -> bit-identical scores).
__global__ __launch_bounds__(256) void k_agg(
    const unsigned short* __restrict__ xp_oth,
    const float* __restrict__ a_own, const float* __restrict__ a_oth,
    const float* __restrict__ bsc,
    const int* __restrict__ rowptr, const int* __restrict__ col,
    unsigned short* __restrict__ Hg, float4* __restrict__ scal,
    int base, int cnt) {
  int local = blockIdx.x * 4 + (threadIdx.x >> 6);
  if (local >= cnt) return;                      // wave-uniform
  int node = base + local;
  int l = threadIdx.x & 63;
  const float ab = a_own[node];
  const float b0 = bsc[0];

  float sum_s = 0.f, mx_s = -1e30f, mn_s = 1e30f;
  float sv0 = 0.f, sv1 = 0.f, sv2 = 0.f, sv3 = 0.f;
  float mv0 = -1e30f, mv1 = -1e30f, mv2 = -1e30f, mv3 = -1e30f;
  int jb = rowptr[node], je = rowptr[node + 1];
  int dg = je - jb;
  int j = jb;
  for (; j + 3 < je; j += 4) {                   // 4 independent gathers
    int o0 = col[j], o1 = col[j + 1], o2 = col[j + 2], o3 = col[j + 3];
    float s0 = __expf(0.f);                      // placeholder overwritten
    s0 = expf(-fabsf((ab + a_oth[o0]) + b0));
    float s1 = expf(-fabsf((ab + a_oth[o1]) + b0));
    float s2 = expf(-fabsf((ab + a_oth[o2]) + b0));
    float s3 = expf(-fabsf((ab + a_oth[o3]) + b0));
    ushort4 g0 = *(const ushort4*)(xp_oth + (size_t)o0 * 256 + 4 * l);
    ushort4 g1 = *(const ushort4*)(xp_oth + (size_t)o1 * 256 + 4 * l);
    ushort4 g2 = *(const ushort4*)(xp_oth + (size_t)o2 * 256 + 4 * l);
    ushort4 g3 = *(const ushort4*)(xp_oth + (size_t)o3 * 256 + 4 * l);
    float f0, f1, f2, f3;
    f0 = bf2f(g0.x); f1 = bf2f(g0.y); f2 = bf2f(g0.z); f3 = bf2f(g0.w);
    sv0 = fmaf(s0, f0, sv0); sv1 = fmaf(s0, f1, sv1);
    sv2 = fmaf(s0, f2, sv2); sv3 = fmaf(s0, f3, sv3);
    mv0 = fmaxf(mv0, s0 * f0); mv1 = fmaxf(mv1, s0 * f1);
    mv2 = fmaxf(mv2, s0 * f2); mv3 = fmaxf(mv3, s0 * f3);
    f0 = bf2f(g1.x); f1 = bf2f(g1.y); f2 = bf2f(g1.z); f3 = bf2f(g1.w);
    sv0 = fmaf(s1, f0, sv0); sv1 = fmaf(s1, f1, sv1);
    sv2 = fmaf(s1, f2, sv2); sv3 = fmaf(s1, f3, sv3);
    mv0 = fmaxf(mv0, s1 * f0); mv1 = fmaxf(mv1, s1 * f1);
    mv2 = fmaxf(mv2, s1 * f2); mv3 = fmaxf(mv3, s1 * f3);
    f0 = bf2f(g2.x); f1 = bf2f(g2.y); f2 = bf2f(g2.z); f3 = bf2f(g2.w);
    sv0 = fmaf(s2, f0, sv0); sv1 = fmaf(s2, f1, sv1);
    sv2 = fmaf(s2, f2, sv2); sv3 = fmaf(s2, f3, sv3);
    mv0 = fmaxf(mv0, s2 * f0); mv1 = fmaxf(mv1, s2 * f1);
    mv2 = fmaxf(mv2, s2 * f2); mv3 = fmaxf(mv3, s2 * f3);
    f0 = bf2f(g3.x); f1 = bf2f(g3.y); f2 = bf2f(g3.z); f3 = bf2f(g3.w);
    sv0 = fmaf(s3, f0, sv0); sv1 = fmaf(s3, f1, sv1);
    sv2 = fmaf(s3, f2, sv2); sv3 = fmaf(s3, f3, sv3);
    mv0 = fmaxf(mv0, s3 * f0); mv1 = fmaxf(mv1, s3 * f1);
    mv2 = fmaxf(mv2, s3 * f2); mv3 = fmaxf(mv3, s3 * f3);
    sum_s += (s0 + s1) + (s2 + s3);
    mx_s = fmaxf(mx_s, fmaxf(fmaxf(s0, s1), fmaxf(s2, s3)));
    mn_s = fminf(mn_s, fminf(fminf(s0, s1), fminf(s2, s3)));
  }
  for (; j < je; ++j) {                          // tail 0..3
    int o0 = col[j];
    float s0 = expf(-fabsf((ab + a_oth[o0]) + b0));
    ushort4 g0 = *(const ushort4*)(xp_oth + (size_t)o0 * 256 + 4 * l);
    float f0 = bf2f(g0.x), f1 = bf2f(g0.y), f2 = bf2f(g0.z), f3 = bf2f(g0.w);
    sv0 = fmaf(s0, f0, sv0); sv1 = fmaf(s0, f1, sv1);
    sv2 = fmaf(s0, f2, sv2); sv3 = fmaf(s0, f3, sv3);
    mv0 = fmaxf(mv0, s0 * f0); mv1 = fmaxf(mv1, s0 * f1);
    mv2 = fmaxf(mv2, s0 * f2); mv3 = fmaxf(mv3, s0 * f3);
    sum_s += s0; mx_s = fmaxf(mx_s, s0); mn_s = fminf(mn_s, s0);
  }
  float inv = 1.f / (float)(dg > 0 ? dg : 1);
  unsigned short* Hr = Hg + (size_t)local * 512;
  *(ushort4*)(Hr + 4 * l) = make_ushort4(
      f2bf(sv0 * inv), f2bf(sv1 * inv), f2bf(sv2 * inv), f2bf(sv3 * inv));
  *(ushort4*)(Hr + 256 + 4 * l) = make_ushort4(
      f2bf(fmaxf(mv0, 0.f)), f2bf(fmaxf(mv1, 0.f)),
      f2bf(fmaxf(mv2, 0.f)), f2bf(fmaxf(mv3, 0.f)));
  if (l == 0)
    scal[local] = make_float4(sum_s * inv, dg > 0 ? mx_s : 0.f,
                              dg > 0 ? mn_s : 0.f, 0.f);
}

// ---- output GEMM, composite A, 128x128, counted-vmcnt pipeline -------------
template <int OWN_FIRST>
__global__ __launch_bounds__(512) void k_gemm_out(
    const float* __restrict__ x, const unsigned short* __restrict__ xp,
    const unsigned short* __restrict__ Hg, const float4* __restrict__ scal,
    const unsigned short* __restrict__ Wt, const float* __restrict__ bias,
    float* __restrict__ out, int Nloc) {
  __shared__ unsigned short Ab[2][128 * 64];    // 16 KB x2
  __shared__ unsigned short Bb[2][128 * 64];    // 16 KB x2
  const int tid = threadIdx.x;
  const int l = tid & 63;
  const int lr = l & 15, lg = l >> 4;
  const int w = tid >> 6;                       // 0..7
  const int wr = w >> 1, wc = w & 1;            // 4 x 2 wave grid
  const int r0 = blockIdx.x * 128;
  const int wbase = tid & 448;                  // w*64, wave-uniform

  int arw[2], acl[2], ar[2], asc[2];
  size_t adst[2];
  float ssv[2], mxv[2], mnv[2];
#pragma unroll
  for (int i = 0; i < 2; ++i) {
    int g = i * 512 + tid;
    arw[i] = g >> 3; acl[i] = g & 7;
    ar[i] = min(r0 + arw[i], Nloc - 1);
    asc[i] = acl[i] ^ (arw[i] & 7);
    adst[i] = (size_t)(arw[i] * 8 + asc[i]) * 8;
    float4 s4 = scal[ar[i]];
    ssv[i] = s4.x; mxv[i] = s4.y; mnv[i] = s4.z;
  }

  auto ptype = [](int t) -> int {
    if (t < 2) return 0;
    if (t < 6) return 1;
    int phase = (t - 6) >> 2;
    int own = OWN_FIRST ? !(phase & 1) : (phase & 1);
    return own ? 2 : 3;
  };
  auto gcnt = [&](int t) -> int {
    if (t > 21) return 0;
    int pt = ptype(t);
    return (pt == 1 || pt == 3) ? 4 : 2;
  };

  float4 px4[2][2];
  bf16x8 pxp[2];

  auto stage_regload = [&](int t) {
    int pt = ptype(t);
    if (pt == 0) {
#pragma unroll
      for (int i = 0; i < 2; ++i) {
        const float* src = x + (size_t)ar[i] * 128 + t * 64 + acl[i] * 8;
        px4[i][0] = *(const float4*)src;
        px4[i][1] = *(const float4*)(src + 4);
      }
    } else if (pt == 2) {
      int sub = (t - 6) & 3;
#pragma unroll
      for (int i = 0; i < 2; ++i)
        pxp[i] = *(const bf16x8*)(xp + (size_t)ar[i] * 256 + sub * 64 +
                                  acl[i] * 8);
    }
  };

  auto stage_gld = [&](int t, int b) {
    int pt = ptype(t);
    if (pt == 1) {
#pragma unroll
      for (int i = 0; i < 2; ++i)
        GLD16(xp + (size_t)ar[i] * 256 + (t - 2) * 64 + asc[i] * 8,
              &Ab[b][(size_t)(i * 512 + wbase) * 8]);
    } else if (pt == 3) {
      int phase = (t - 6) >> 2, sub = (t - 6) & 3;
      int hoff = (phase >= 2 ? 256 : 0) + sub * 64;
#pragma unroll
      for (int i = 0; i < 2; ++i)
        GLD16(Hg + (size_t)ar[i] * 512 + hoff + asc[i] * 8,
              &Ab[b][(size_t)(i * 512 + wbase) * 8]);
    }
    int kb = t * 64;                             // B (128 rows x 64 cols)
#pragma unroll
    for (int i = 0; i < 2; ++i) {
      int g = i * 512 + tid;
      int row = g >> 3, c = g & 7;
      int sc = c ^ (row & 7);
      GLD16(Wt + (size_t)row * 1408 + kb + sc * 8,
            &Bb[b][(size_t)(i * 512 + wbase) * 8]);
    }
  };

  auto stage_write = [&](int t, int b) {
    int pt = ptype(t);
    if (pt == 0) {
#pragma unroll
      for (int i = 0; i < 2; ++i) {
        bf16x8 h;
        h[0] = (short)f2bf(px4[i][0].x); h[1] = (short)f2bf(px4[i][0].y);
        h[2] = (short)f2bf(px4[i][0].z); h[3] = (short)f2bf(px4[i][0].w);
        h[4] = (short)f2bf(px4[i][1].x); h[5] = (short)f2bf(px4[i][1].y);
        h[6] = (short)f2bf(px4[i][1].z); h[7] = (short)f2bf(px4[i][1].w);
        *(bf16x8*)&Ab[b][adst[i]] = h;
      }
    } else if (pt == 2) {
      int phase = (t - 6) >> 2;
#pragma unroll
      for (int i = 0; i < 2; ++i) {
        bf16x8 h;
        if (phase < 2) {                         // own-mean = ss * xp
#pragma unroll
          for (int q = 0; q < 8; ++q)
            h[q] = (short)f2bf(bf2f((unsigned short)pxp[i][q]) * ssv[i]);
        } else {                                 // own-max = clamp form
#pragma unroll
          for (int q = 0; q < 8; ++q) {
            float f = bf2f((unsigned short)pxp[i][q]);
            h[q] = (short)f2bf(fmaxf(fmaxf(f * mxv[i], f * mnv[i]), 0.f));
          }
        }
        *(bf16x8*)&Ab[b][adst[i]] = h;
      }
    }
  };

  f32x4 acc[2][4];
#pragma unroll
  for (int m = 0; m < 2; ++m)
#pragma unroll
    for (int t = 0; t < 4; ++t) {
      f32x4 z = {0.f, 0.f, 0.f, 0.f};
      acc[m][t] = z;
    }

  auto compute = [&](int b) {
#pragma unroll
    for (int kk = 0; kk < 2; ++kk) {
      int chq = kk * 4 + lg;
      bf16x8 a[2], bt[4];
#pragma unroll
      for (int m = 0; m < 2; ++m) {
        int row = wr * 32 + m * 16 + lr;
        a[m] = *(const bf16x8*)&Ab[b][(row * 8 + (chq ^ (row & 7))) * 8];
      }
#pragma unroll
      for (int t = 0; t < 4; ++t) {
        int row = wc * 64 + t * 16 + lr;
        bt[t] = *(const bf16x8*)&Bb[b][(row * 8 + (chq ^ (row & 7))) * 8];
      }
#pragma unroll
      for (int m = 0; m < 2; ++m)
#pragma unroll
        for (int t = 0; t < 4; ++t)
          acc[m][t] = __builtin_amdgcn_mfma_f32_16x16x32_bf16(
              a[m], bt[t], acc[m][t], 0, 0, 0);
    }
  };

  auto wait_cnt = [&](int n) {
    if (n >= 4)
      asm volatile("s_waitcnt vmcnt(4) lgkmcnt(0)" ::: "memory");
    else if (n >= 2)
      asm volatile("s_waitcnt vmcnt(2) lgkmcnt(0)" ::: "memory");
    else
      asm volatile("s_waitcnt vmcnt(0) lgkmcnt(0)" ::: "memory");
  };

  stage_regload(0); stage_gld(0, 0); stage_write(0, 0);
  stage_regload(1); stage_gld(1, 1); stage_write(1, 1);

  for (int t = 0; t < 22; ++t) {
    int b = t & 1;
    wait_cnt(gcnt(t + 1));                      // buf t ready; t+1 in flight
    __builtin_amdgcn_s_barrier();
    __builtin_amdgcn_sched_barrier(0);
    if (t + 2 <= 21) stage_regload(t + 2);
    compute(b);
    __builtin_amdgcn_s_barrier();
    __builtin_amdgcn_sched_barrier(0);
    if (t + 2 <= 21) {
      stage_gld(t + 2, b);
      stage_write(t + 2, b);
    }
  }
  asm volatile("s_waitcnt vmcnt(0) lgkmcnt(0)" ::: "memory");

#pragma unroll
  for (int m = 0; m < 2; ++m) {
    int rb = r0 + wr * 32 + m * 16 + lg * 4;    // C/D: col=lane&15, row=lg*4+reg
#pragma unroll
    for (int t = 0; t < 4; ++t) {
      int c = wc * 64 + t * 16 + lr;
      float bbias = bias[c];
#pragma unroll
      for (int r = 0; r < 4; ++r) {
        int rr = rb + r;
        if (rr < Nloc) out[(size_t)rr * 128 + c] = fmaxf(acc[m][t][r] + bbias, 0.f);
      }
    }
  }
}

extern "C" void kernel_launch(void* const* d_in, const int* in_sizes, int n_in,
                              void* d_out, int out_size, void* d_ws,
                              size_t ws_size, hipStream_t stream) {
  const float* x_i  = (const float*)d_in[0];
  const float* x_m  = (const float*)d_in[1];
  const int*   ei   = (const int*)d_in[2];
  const float* Wi_i = (const float*)d_in[3];
  const float* bi_i = (const float*)d_in[4];
  const float* Wi_m = (const float*)d_in[5];
  const float* bi_m = (const float*)d_in[6];
  const float* Wsc  = (const float*)d_in[7];
  const float* bsc  = (const float*)d_in[8];
  const float* Wo_i = (const float*)d_in[9];
  const float* bo_i = (const float*)d_in[10];
  const float* Wo_m = (const float*)d_in[11];
  const float* bo_m = (const float*)d_in[12];
  float* out = (float*)d_out;

  int Ni = in_sizes[0] / 128, Nm = in_sizes[1] / 128, E = in_sizes[2] / 2;
  const int* es = ei;
  const int* ee = ei + E;
  int nbi = (Ni + 255) / 256, nbm = (Nm + 255) / 256;   // <= 1024 assumed

  char* p = (char*)d_ws;
  auto alloc = [&](size_t bytes) {
    char* q = p;
    p += (bytes + 255) & ~(size_t)255;
    return q;
  };
  unsigned short* xp_i = (unsigned short*)alloc((size_t)Ni * 256 * 2);
  unsigned short* xp_m = (unsigned short*)alloc((size_t)Nm * 256 * 2);
  float* a_i   = (float*)alloc((size_t)Ni * 4);
  float* a_m   = (float*)alloc((size_t)Nm * 4);
  int* deg_i   = (int*)alloc((size_t)Ni * 4);
  int* deg_m   = (int*)alloc((size_t)Nm * 4);
  int* rp_i    = (int*)alloc((size_t)(Ni + 1) * 4);
  int* rp_m    = (int*)alloc((size_t)(Nm + 1) * 4);
  int* cur_i   = (int*)alloc((size_t)Ni * 4);
  int* cur_m   = (int*)alloc((size_t)Nm * 4);
  int* bs_i    = (int*)alloc((size_t)nbi * 4);
  int* bs_m    = (int*)alloc((size_t)nbm * 4);
  int* bb_i    = (int*)alloc((size_t)nbi * 4);
  int* bb_m    = (int*)alloc((size_t)nbm * 4);
  int* col_i   = (int*)alloc((size_t)E * 4);
  int* col_m   = (int*)alloc((size_t)E * 4);
  unsigned short* Wt_i = (unsigned short*)alloc((size_t)128 * 1408 * 2);
  unsigned short* Wt_m = (unsigned short*)alloc((size_t)128 * 1408 * 2);
  unsigned short* Wint_i = (unsigned short*)alloc((size_t)256 * 128 * 2);
  unsigned short* Wint_m = (unsigned short*)alloc((size_t)256 * 128 * 2);

  size_t used = (size_t)(p - (char*)d_ws);
  if (used + 256 > ws_size) return;
  size_t avail = ws_size - used - 256;
  long long srows_ll = (long long)(avail / 1040);
  int maxN = (Ni > Nm ? Ni : Nm);
  int maxPad = (maxN + 127) & ~127;
  int S = (int)(srows_ll > maxPad ? maxPad : srows_ll);
  S &= ~127;
  if (S < 128) return;
  unsigned short* Hg = (unsigned short*)alloc((size_t)S * 512 * 2);
  float4* scal = (float4*)alloc((size_t)S * 16);

  hipMemsetAsync(deg_i, 0, (size_t)Ni * 4, stream);
  hipMemsetAsync(deg_m, 0, (size_t)Nm * 4, stream);
  hipMemsetAsync(a_i, 0, (size_t)Ni * 4, stream);
  hipMemsetAsync(a_m, 0, (size_t)Nm * 4, stream);

  k_prep_wt<<<(1408 * 128 + 255) / 256, 256, 0, stream>>>(Wo_i, Wt_i, 1408, 128);
  k_prep_wt<<<(1408 * 128 + 255) / 256, 256, 0, stream>>>(Wo_m, Wt_m, 1408, 128);
  k_prep_wt<<<(128 * 256 + 255) / 256, 256, 0, stream>>>(Wi_i, Wint_i, 128, 256);
  k_prep_wt<<<(128 * 256 + 255) / 256, 256, 0, stream>>>(Wi_m, Wint_m, 128, 256);

  k_gemm_in<<<(Ni + 63) / 64, 256, 0, stream>>>(x_i, Wint_i, bi_i, Wsc, xp_i, a_i, Ni);
  k_gemm_in<<<(Nm + 63) / 64, 256, 0, stream>>>(x_m, Wint_m, bi_m, Wsc + 256, xp_m, a_m, Nm);

  k_deg<<<(E + 255) / 256, 256, 0, stream>>>(es, ee, E, deg_i, deg_m);
  k_scan_blk<<<nbi, 256, 0, stream>>>(deg_i, bs_i, Ni);
  k_scan_blk<<<nbm, 256, 0, stream>>>(deg_m, bs_m, Nm);
  k_scan_top<<<2, 1024, 0, stream>>>(bs_i, bb_i, nbi, bs_m, bb_m, nbm);
  k_scan_wr<<<nbi, 256, 0, stream>>>(deg_i, bb_i, rp_i, cur_i, Ni, E);
  k_scan_wr<<<nbm, 256, 0, stream>>>(deg_m, bb_m, rp_m, cur_m, Nm, E);
  k_fill<<<(E + 255) / 256, 256, 0, stream>>>(es, ee, E, cur_i, col_i,
                                              cur_m, col_m);

  // intt side: own halves first in pooled blocks (OWN_FIRST=1)
  for (int base = 0; base < Ni; base += S) {
    int cnt = Ni - base; if (cnt > S) cnt = S;
    k_agg<<<(cnt + 3) / 4, 256, 0, stream>>>(xp_m, a_i, a_m, bsc, rp_i, col_i,
                                             Hg, scal, base, cnt);
    k_gemm_out<1><<<(cnt + 127) / 128, 512, 0, stream>>>(
        x_i + (size_t)base * 128, xp_i + (size_t)base * 256, Hg, scal,
        Wt_i, bo_i, out + (size_t)base * 128, cnt);
  }
  // mvtx side: gathered halves first (OWN_FIRST=0)
  float* out_m = out + (size_t)Ni * 128;
  for (int base = 0; base < Nm; base += S) {
    int cnt = Nm - base; if (cnt > S) cnt = S;
    k_agg<<<(cnt + 3) / 4, 256, 0, stream>>>(xp_i, a_m, a_i, bsc, rp_m, col_m,
                                             Hg, scal, base, cnt);
    k_gemm_out<0><<<(cnt + 127) / 128, 512, 0, stream>>>(
        x_m + (size_t)base * 128, xp_m + (size_t)base * 256, Hg, scal,
        Wt_m, bo_m, out_m + (size_t)base * 128, cnt);
  }
}

// Round 19
// 254.919 us; speedup vs baseline: 1.0726x; 1.0726x over previous
//
#include <hip/hip_runtime.h>

// ---------------------------------------------------------------------------
// BipartiteLayer: xp = x@W_in+b ; s = exp(-|[xp_i[s],xp_m[e]]@W_score+b|) ;
// scatter mean/max of xp_pair*s ; h = relu([x,xp,mean,max]@W_out+b)
//
// R19: dispatch fusion (21 -> 12 launches). No numerical changes:
//  - one memset over contiguous [a_i|a_m|deg_i|deg_m]
//  - k_prep_all: 4 weight transposes in one segmented launch
//  - k_gemm_in: both sides in one segmented launch
//  - k_scan_blk / k_scan_wr: both sides per launch
// k_agg / k_gemm_out / k_deg / k_scan_top / k_fill bodies unchanged (R18).
// ---------------------------------------------------------------------------

typedef __attribute__((ext_vector_type(8))) short bf16x8;   // 8 bf16 = 4 VGPR
typedef __attribute__((ext_vector_type(4))) float f32x4;

static __device__ __forceinline__ unsigned short f2bf(float f) {
  unsigned int u = __float_as_uint(f);
  u = (u + 0x7FFFu + ((u >> 16) & 1u)) >> 16;   // RNE
  return (unsigned short)u;
}
static __device__ __forceinline__ float bf2f(unsigned short s) {
  return __uint_as_float(((unsigned int)s) << 16);
}

#define GLD16(gp, lp)                                                        \
  __builtin_amdgcn_global_load_lds(                                          \
      (const __attribute__((address_space(1))) void*)(gp),                   \
      (__attribute__((address_space(3))) void*)(lp), 16, 0, 0)

// ---- fused transpose of all 4 weight matrices ------------------------------
// seg 0: Wo_i (1408x128), seg 1: Wo_m (1408x128),
// seg 2: Wi_i (128x256),  seg 3: Wi_m (128x256). 256 thr/block.
__global__ void k_prep_all(const float* __restrict__ Wo_i,
                           unsigned short* __restrict__ Wt_i,
                           const float* __restrict__ Wo_m,
                           unsigned short* __restrict__ Wt_m,
                           const float* __restrict__ Wi_i,
                           unsigned short* __restrict__ Wint_i,
                           const float* __restrict__ Wi_m,
                           unsigned short* __restrict__ Wint_m) {
  const int NB_O = (1408 * 128 + 255) / 256;    // 704
  const int NB_I = (128 * 256 + 255) / 256;     // 128
  int bid = blockIdx.x;
  const float* src;
  unsigned short* dst;
  int K, Ncol, nelem;
  if (bid < NB_O) {
    src = Wo_i; dst = Wt_i; K = 1408; Ncol = 128; nelem = 1408 * 128;
  } else if (bid < 2 * NB_O) {
    bid -= NB_O;
    src = Wo_m; dst = Wt_m; K = 1408; Ncol = 128; nelem = 1408 * 128;
  } else if (bid < 2 * NB_O + NB_I) {
    bid -= 2 * NB_O;
    src = Wi_i; dst = Wint_i; K = 128; Ncol = 256; nelem = 128 * 256;
  } else {
    bid -= 2 * NB_O + NB_I;
    src = Wi_m; dst = Wint_m; K = 128; Ncol = 256; nelem = 128 * 256;
  }
  int idx = bid * 256 + threadIdx.x;
  if (idx >= nelem) return;
  int k = idx / Ncol, c = idx % Ncol;
  dst[(size_t)c * K + k] = f2bf(src[idx]);
}

// ---- input GEMM (MFMA), both sides segmented -------------------------------
__global__ __launch_bounds__(256) void k_gemm_in(
    const float* __restrict__ x_i, const unsigned short* __restrict__ Wint_i,
    const float* __restrict__ bi_i, unsigned short* __restrict__ xp_i,
    float* __restrict__ a_i, int Ni, int nblk_i,
    const float* __restrict__ x_m, const unsigned short* __restrict__ Wint_m,
    const float* __restrict__ bi_m, unsigned short* __restrict__ xp_m,
    float* __restrict__ a_m, int Nm, const float* __restrict__ Wsc) {
  const float* x; const unsigned short* Wint; const float* bias;
  const float* Wscp; unsigned short* xp; float* a_out; int N, bid;
  if ((int)blockIdx.x < nblk_i) {
    x = x_i; Wint = Wint_i; bias = bi_i; Wscp = Wsc;
    xp = xp_i; a_out = a_i; N = Ni; bid = blockIdx.x;
  } else {
    x = x_m; Wint = Wint_m; bias = bi_m; Wscp = Wsc + 256;
    xp = xp_m; a_out = a_m; N = Nm; bid = blockIdx.x - nblk_i;
  }
  __shared__ __align__(16) unsigned short Ab[64 * 16 * 8];    // 16 KB
  __shared__ __align__(16) unsigned short Bb[256 * 16 * 8];   // 64 KB
  const int tid = threadIdx.x;
  const int l = tid & 63;
  const int lr = l & 15, lg = l >> 4;
  const int w = tid >> 6, wr = w >> 1, wc = w & 1;
  const int r0 = bid * 64;
  const int wbase = tid & 192;                  // w*64, wave-uniform

#pragma unroll
  for (int i = 0; i < 16; ++i) {                // B: 256 rows x 16 chunks
    int g = i * 256 + tid;
    int row = g >> 4, c = g & 15;
    int sc = c ^ (row & 7);
    GLD16(Wint + (size_t)row * 128 + sc * 8,
          &Bb[(size_t)(i * 256 + wbase) * 8]);
  }
#pragma unroll
  for (int i = 0; i < 4; ++i) {                 // A: reg-stage f32->bf16
    int g = i * 256 + tid;
    int row = g >> 4, c = g & 15;
    int ar = min(r0 + row, N - 1);
    const float* src = x + (size_t)ar * 128 + c * 8;
    float4 u = *(const float4*)src;
    float4 v = *(const float4*)(src + 4);
    bf16x8 h;
    h[0] = (short)f2bf(u.x); h[1] = (short)f2bf(u.y);
    h[2] = (short)f2bf(u.z); h[3] = (short)f2bf(u.w);
    h[4] = (short)f2bf(v.x); h[5] = (short)f2bf(v.y);
    h[6] = (short)f2bf(v.z); h[7] = (short)f2bf(v.w);
    *(bf16x8*)&Ab[(size_t)(row * 16 + (c ^ (row & 7))) * 8] = h;
  }
  __syncthreads();

  f32x4 acc[2][8];
#pragma unroll
  for (int m = 0; m < 2; ++m)
#pragma unroll
    for (int t = 0; t < 8; ++t) {
      f32x4 z = {0.f, 0.f, 0.f, 0.f};
      acc[m][t] = z;
    }
#pragma unroll
  for (int kk = 0; kk < 4; ++kk) {
    int chq = kk * 4 + lg;
    bf16x8 a[2], bt[8];
#pragma unroll
    for (int m = 0; m < 2; ++m) {
      int row = wr * 32 + m * 16 + lr;
      a[m] = *(const bf16x8*)&Ab[(row * 16 + (chq ^ (row & 7))) * 8];
    }
#pragma unroll
    for (int t = 0; t < 8; ++t) {
      int row = wc * 128 + t * 16 + lr;
      bt[t] = *(const bf16x8*)&Bb[(row * 16 + (chq ^ (row & 7))) * 8];
    }
#pragma unroll
    for (int m = 0; m < 2; ++m)
#pragma unroll
      for (int t = 0; t < 8; ++t)
        acc[m][t] = __builtin_amdgcn_mfma_f32_16x16x32_bf16(
            a[m], bt[t], acc[m][t], 0, 0, 0);
  }

  float wscv[8], bb[8];
#pragma unroll
  for (int t = 0; t < 8; ++t) {
    int c = wc * 128 + t * 16 + lr;
    wscv[t] = Wscp[c];
    bb[t] = bias[c];
  }
#pragma unroll
  for (int m = 0; m < 2; ++m) {
    int rb = r0 + wr * 32 + m * 16 + lg * 4;    // C/D: col=lane&15, row=lg*4+reg
    float p0 = 0.f, p1 = 0.f, p2 = 0.f, p3 = 0.f;
#pragma unroll
    for (int t = 0; t < 8; ++t) {
      int c = wc * 128 + t * 16 + lr;
      float v0 = acc[m][t][0] + bb[t];
      float v1 = acc[m][t][1] + bb[t];
      float v2 = acc[m][t][2] + bb[t];
      float v3 = acc[m][t][3] + bb[t];
      if (rb + 0 < N) xp[(size_t)(rb + 0) * 256 + c] = f2bf(v0);
      if (rb + 1 < N) xp[(size_t)(rb + 1) * 256 + c] = f2bf(v1);
      if (rb + 2 < N) xp[(size_t)(rb + 2) * 256 + c] = f2bf(v2);
      if (rb + 3 < N) xp[(size_t)(rb + 3) * 256 + c] = f2bf(v3);
      p0 = fmaf(v0, wscv[t], p0); p1 = fmaf(v1, wscv[t], p1);
      p2 = fmaf(v2, wscv[t], p2); p3 = fmaf(v3, wscv[t], p3);
    }
#pragma unroll
    for (int off = 1; off < 16; off <<= 1) {
      p0 += __shfl_xor(p0, off); p1 += __shfl_xor(p1, off);
      p2 += __shfl_xor(p2, off); p3 += __shfl_xor(p3, off);
    }
    if (lr == 0) {
      if (rb + 0 < N) atomicAdd(a_out + rb + 0, p0);
      if (rb + 1 < N) atomicAdd(a_out + rb + 1, p1);
      if (rb + 2 < N) atomicAdd(a_out + rb + 2, p2);
      if (rb + 3 < N) atomicAdd(a_out + rb + 3, p3);
    }
  }
}

// ---- CSR build: degree histogram ------------------------------------------
__global__ void k_deg(const int* __restrict__ es, const int* __restrict__ ee,
                      int E, int* __restrict__ deg_i, int* __restrict__ deg_m) {
  int e = blockIdx.x * blockDim.x + threadIdx.x;
  if (e >= E) return;
  atomicAdd(deg_i + es[e], 1);
  atomicAdd(deg_m + ee[e], 1);
}

// ---- CSR scan phase 1 (both sides in one launch) ---------------------------
__global__ __launch_bounds__(256) void k_scan_blk(
    const int* __restrict__ deg_i, int* __restrict__ bs_i, int Ni, int nbi,
    const int* __restrict__ deg_m, int* __restrict__ bs_m, int Nm) {
  const int* deg; int* bs; int n, bid;
  if ((int)blockIdx.x < nbi) { deg = deg_i; bs = bs_i; n = Ni; bid = blockIdx.x; }
  else { deg = deg_m; bs = bs_m; n = Nm; bid = blockIdx.x - nbi; }
  __shared__ int sm[256];
  int t = threadIdx.x;
  int i = bid * 256 + t;
  sm[t] = (i < n) ? deg[i] : 0;
  __syncthreads();
#pragma unroll
  for (int off = 128; off; off >>= 1) {
    if (t < off) sm[t] += sm[t + off];
    __syncthreads();
  }
  if (t == 0) bs[bid] = sm[0];
}

// ---- CSR scan phase 2 ------------------------------------------------------
__global__ __launch_bounds__(1024) void k_scan_top(
    const int* __restrict__ bs_i, int* __restrict__ bb_i, int nbi,
    const int* __restrict__ bs_m, int* __restrict__ bb_m, int nbm) {
  const int* bs = blockIdx.x ? bs_m : bs_i;
  int* bb = blockIdx.x ? bb_m : bb_i;
  int nb = blockIdx.x ? nbm : nbi;
  __shared__ int sm[1024];
  int t = threadIdx.x;
  int d = (t < nb) ? bs[t] : 0;
  sm[t] = d;
  __syncthreads();
  for (int off = 1; off < 1024; off <<= 1) {    // Hillis-Steele inclusive
    int v = (t >= off) ? sm[t - off] : 0;
    __syncthreads();
    sm[t] += v;
    __syncthreads();
  }
  if (t < nb) bb[t] = sm[t] - d;                // exclusive
}

// ---- CSR scan phase 3 (both sides in one launch) ---------------------------
__global__ __launch_bounds__(256) void k_scan_wr(
    const int* __restrict__ deg_i, const int* __restrict__ bb_i,
    int* __restrict__ rp_i, int* __restrict__ cur_i, int Ni, int nbi,
    const int* __restrict__ deg_m, const int* __restrict__ bb_m,
    int* __restrict__ rp_m, int* __restrict__ cur_m, int Nm, int E) {
  const int* deg; const int* bb; int* rp; int* cur; int n, bid;
  if ((int)blockIdx.x < nbi) {
    deg = deg_i; bb = bb_i; rp = rp_i; cur = cur_i; n = Ni; bid = blockIdx.x;
  } else {
    deg = deg_m; bb = bb_m; rp = rp_m; cur = cur_m; n = Nm;
    bid = blockIdx.x - nbi;
  }
  __shared__ int sm[256];
  int t = threadIdx.x;
  int i = bid * 256 + t;
  int d = (i < n) ? deg[i] : 0;
  sm[t] = d;
  __syncthreads();
  for (int off = 1; off < 256; off <<= 1) {     // Hillis-Steele inclusive
    int v = (t >= off) ? sm[t - off] : 0;
    __syncthreads();
    sm[t] += v;
    __syncthreads();
  }
  if (i < n) {
    int v = bb[bid] + sm[t] - d;                // exclusive + block base
    rp[i] = v; cur[i] = v;
  }
  if (i == 0) rp[n] = E;
}

// ---- CSR build: fill (col only; scores recomputed in k_agg) ----------------
__global__ void k_fill(const int* __restrict__ es, const int* __restrict__ ee,
                       int E, int* __restrict__ cur_i, int* __restrict__ col_i,
                       int* __restrict__ cur_m, int* __restrict__ col_m) {
  int e = blockIdx.x * blockDim.x + threadIdx.x;
  if (e >= E) return;
  int s = es[e], m = ee[e];
  int pi = atomicAdd(cur_i + s, 1);
  col_i[pi] = m;
  int pm = atomicAdd(cur_m + m, 1);
  col_m[pm] = s;
}

// ---- wave-per-node CSR aggregation -> Hg (512 gathered cols) + scal --------
__global__ __launch_bounds__(256) void k_agg(
    const unsigned short* __restrict__ xp_oth,
    const float* __restrict__ a_own, const float* __restrict__ a_oth,
    const float* __restrict__ bsc,
    const int* __restrict__ rowptr, const int* __restrict__ col,
    unsigned short* __restrict__ Hg, float4* __restrict__ scal,
    int base, int cnt) {
  int local = blockIdx.x * 4 + (threadIdx.x >> 6);
  if (local >= cnt) return;                      // wave-uniform
  int node = base + local;
  int l = threadIdx.x & 63;
  const float ab = a_own[node];
  const float b0 = bsc[0];

  float sum_s = 0.f, mx_s = -1e30f, mn_s = 1e30f;
  float sv0 = 0.f, sv1 = 0.f, sv2 = 0.f, sv3 = 0.f;
  float mv0 = -1e30f, mv1 = -1e30f, mv2 = -1e30f, mv3 = -1e30f;
  int jb = rowptr[node], je = rowptr[node + 1];
  int dg = je - jb;
  int j = jb;
  for (; j + 3 < je; j += 4) {                   // 4 independent gathers
    int o0 = col[j], o1 = col[j + 1], o2 = col[j + 2], o3 = col[j + 3];
    float s0 = expf(-fabsf((ab + a_oth[o0]) + b0));
    float s1 = expf(-fabsf((ab + a_oth[o1]) + b0));
    float s2 = expf(-fabsf((ab + a_oth[o2]) + b0));
    float s3 = expf(-fabsf((ab + a_oth[o3]) + b0));
    ushort4 g0 = *(const ushort4*)(xp_oth + (size_t)o0 * 256 + 4 * l);
    ushort4 g1 = *(const ushort4*)(xp_oth + (size_t)o1 * 256 + 4 * l);
    ushort4 g2 = *(const ushort4*)(xp_oth + (size_t)o2 * 256 + 4 * l);
    ushort4 g3 = *(const ushort4*)(xp_oth + (size_t)o3 * 256 + 4 * l);
    float f0, f1, f2, f3;
    f0 = bf2f(g0.x); f1 = bf2f(g0.y); f2 = bf2f(g0.z); f3 = bf2f(g0.w);
    sv0 = fmaf(s0, f0, sv0); sv1 = fmaf(s0, f1, sv1);
    sv2 = fmaf(s0, f2, sv2); sv3 = fmaf(s0, f3, sv3);
    mv0 = fmaxf(mv0, s0 * f0); mv1 = fmaxf(mv1, s0 * f1);
    mv2 = fmaxf(mv2, s0 * f2); mv3 = fmaxf(mv3, s0 * f3);
    f0 = bf2f(g1.x); f1 = bf2f(g1.y); f2 = bf2f(g1.z); f3 = bf2f(g1.w);
    sv0 = fmaf(s1, f0, sv0); sv1 = fmaf(s1, f1, sv1);
    sv2 = fmaf(s1, f2, sv2); sv3 = fmaf(s1, f3, sv3);
    mv0 = fmaxf(mv0, s1 * f0); mv1 = fmaxf(mv1, s1 * f1);
    mv2 = fmaxf(mv2, s1 * f2); mv3 = fmaxf(mv3, s1 * f3);
    f0 = bf2f(g2.x); f1 = bf2f(g2.y); f2 = bf2f(g2.z); f3 = bf2f(g2.w);
    sv0 = fmaf(s2, f0, sv0); sv1 = fmaf(s2, f1, sv1);
    sv2 = fmaf(s2, f2, sv2); sv3 = fmaf(s2, f3, sv3);
    mv0 = fmaxf(mv0, s2 * f0); mv1 = fmaxf(mv1, s2 * f1);
    mv2 = fmaxf(mv2, s2 * f2); mv3 = fmaxf(mv3, s2 * f3);
    f0 = bf2f(g3.x); f1 = bf2f(g3.y); f2 = bf2f(g3.z); f3 = bf2f(g3.w);
    sv0 = fmaf(s3, f0, sv0); sv1 = fmaf(s3, f1, sv1);
    sv2 = fmaf(s3, f2, sv2); sv3 = fmaf(s3, f3, sv3);
    mv0 = fmaxf(mv0, s3 * f0); mv1 = fmaxf(mv1, s3 * f1);
    mv2 = fmaxf(mv2, s3 * f2); mv3 = fmaxf(mv3, s3 * f3);
    sum_s += (s0 + s1) + (s2 + s3);
    mx_s = fmaxf(mx_s, fmaxf(fmaxf(s0, s1), fmaxf(s2, s3)));
    mn_s = fminf(mn_s, fminf(fminf(s0, s1), fminf(s2, s3)));
  }
  for (; j < je; ++j) {                          // tail 0..3
    int o0 = col[j];
    float s0 = expf(-fabsf((ab + a_oth[o0]) + b0));
    ushort4 g0 = *(const ushort4*)(xp_oth + (size_t)o0 * 256 + 4 * l);
    float f0 = bf2f(g0.x), f1 = bf2f(g0.y), f2 = bf2f(g0.z), f3 = bf2f(g0.w);
    sv0 = fmaf(s0, f0, sv0); sv1 = fmaf(s0, f1, sv1);
    sv2 = fmaf(s0, f2, sv2); sv3 = fmaf(s0, f3, sv3);
    mv0 = fmaxf(mv0, s0 * f0); mv1 = fmaxf(mv1, s0 * f1);
    mv2 = fmaxf(mv2, s0 * f2); mv3 = fmaxf(mv3, s0 * f3);
    sum_s += s0; mx_s = fmaxf(mx_s, s0); mn_s = fminf(mn_s, s0);
  }
  float inv = 1.f / (float)(dg > 0 ? dg : 1);
  unsigned short* Hr = Hg + (size_t)local * 512;
  *(ushort4*)(Hr + 4 * l) = make_ushort4(
      f2bf(sv0 * inv), f2bf(sv1 * inv), f2bf(sv2 * inv), f2bf(sv3 * inv));
  *(ushort4*)(Hr + 256 + 4 * l) = make_ushort4(
      f2bf(fmaxf(mv0, 0.f)), f2bf(fmaxf(mv1, 0.f)),
      f2bf(fmaxf(mv2, 0.f)), f2bf(fmaxf(mv3, 0.f)));
  if (l == 0)
    scal[local] = make_float4(sum_s * inv, dg > 0 ? mx_s : 0.f,
                              dg > 0 ? mn_s : 0.f, 0.f);
}

// ---- output GEMM, composite A, 128x128, counted-vmcnt pipeline -------------
template <int OWN_FIRST>
__global__ __launch_bounds__(512) void k_gemm_out(
    const float* __restrict__ x, const unsigned short* __restrict__ xp,
    const unsigned short* __restrict__ Hg, const float4* __restrict__ scal,
    const unsigned short* __restrict__ Wt, const float* __restrict__ bias,
    float* __restrict__ out, int Nloc) {
  __shared__ unsigned short Ab[2][128 * 64];    // 16 KB x2
  __shared__ unsigned short Bb[2][128 * 64];    // 16 KB x2
  const int tid = threadIdx.x;
  const int l = tid & 63;
  const int lr = l & 15, lg = l >> 4;
  const int w = tid >> 6;                       // 0..7
  const int wr = w >> 1, wc = w & 1;            // 4 x 2 wave grid
  const int r0 = blockIdx.x * 128;
  const int wbase = tid & 448;                  // w*64, wave-uniform

  int arw[2], acl[2], ar[2], asc[2];
  size_t adst[2];
  float ssv[2], mxv[2], mnv[2];
#pragma unroll
  for (int i = 0; i < 2; ++i) {
    int g = i * 512 + tid;
    arw[i] = g >> 3; acl[i] = g & 7;
    ar[i] = min(r0 + arw[i], Nloc - 1);
    asc[i] = acl[i] ^ (arw[i] & 7);
    adst[i] = (size_t)(arw[i] * 8 + asc[i]) * 8;
    float4 s4 = scal[ar[i]];
    ssv[i] = s4.x; mxv[i] = s4.y; mnv[i] = s4.z;
  }

  auto ptype = [](int t) -> int {
    if (t < 2) return 0;
    if (t < 6) return 1;
    int phase = (t - 6) >> 2;
    int own = OWN_FIRST ? !(phase & 1) : (phase & 1);
    return own ? 2 : 3;
  };
  auto gcnt = [&](int t) -> int {
    if (t > 21) return 0;
    int pt = ptype(t);
    return (pt == 1 || pt == 3) ? 4 : 2;
  };

  float4 px4[2][2];
  bf16x8 pxp[2];

  auto stage_regload = [&](int t) {
    int pt = ptype(t);
    if (pt == 0) {
#pragma unroll
      for (int i = 0; i < 2; ++i) {
        const float* src = x + (size_t)ar[i] * 128 + t * 64 + acl[i] * 8;
        px4[i][0] = *(const float4*)src;
        px4[i][1] = *(const float4*)(src + 4);
      }
    } else if (pt == 2) {
      int sub = (t - 6) & 3;
#pragma unroll
      for (int i = 0; i < 2; ++i)
        pxp[i] = *(const bf16x8*)(xp + (size_t)ar[i] * 256 + sub * 64 +
                                  acl[i] * 8);
    }
  };

  auto stage_gld = [&](int t, int b) {
    int pt = ptype(t);
    if (pt == 1) {
#pragma unroll
      for (int i = 0; i < 2; ++i)
        GLD16(xp + (size_t)ar[i] * 256 + (t - 2) * 64 + asc[i] * 8,
              &Ab[b][(size_t)(i * 512 + wbase) * 8]);
    } else if (pt == 3) {
      int phase = (t - 6) >> 2, sub = (t - 6) & 3;
      int hoff = (phase >= 2 ? 256 : 0) + sub * 64;
#pragma unroll
      for (int i = 0; i < 2; ++i)
        GLD16(Hg + (size_t)ar[i] * 512 + hoff + asc[i] * 8,
              &Ab[b][(size_t)(i * 512 + wbase) * 8]);
    }
    int kb = t * 64;                             // B (128 rows x 64 cols)
#pragma unroll
    for (int i = 0; i < 2; ++i) {
      int g = i * 512 + tid;
      int row = g >> 3, c = g & 7;
      int sc = c ^ (row & 7);
      GLD16(Wt + (size_t)row * 1408 + kb + sc * 8,
            &Bb[b][(size_t)(i * 512 + wbase) * 8]);
    }
  };

  auto stage_write = [&](int t, int b) {
    int pt = ptype(t);
    if (pt == 0) {
#pragma unroll
      for (int i = 0; i < 2; ++i) {
        bf16x8 h;
        h[0] = (short)f2bf(px4[i][0].x); h[1] = (short)f2bf(px4[i][0].y);
        h[2] = (short)f2bf(px4[i][0].z); h[3] = (short)f2bf(px4[i][0].w);
        h[4] = (short)f2bf(px4[i][1].x); h[5] = (short)f2bf(px4[i][1].y);
        h[6] = (short)f2bf(px4[i][1].z); h[7] = (short)f2bf(px4[i][1].w);
        *(bf16x8*)&Ab[b][adst[i]] = h;
      }
    } else if (pt == 2) {
      int phase = (t - 6) >> 2;
#pragma unroll
      for (int i = 0; i < 2; ++i) {
        bf16x8 h;
        if (phase < 2) {                         // own-mean = ss * xp
#pragma unroll
          for (int q = 0; q < 8; ++q)
            h[q] = (short)f2bf(bf2f((unsigned short)pxp[i][q]) * ssv[i]);
        } else {                                 // own-max = clamp form
#pragma unroll
          for (int q = 0; q < 8; ++q) {
            float f = bf2f((unsigned short)pxp[i][q]);
            h[q] = (short)f2bf(fmaxf(fmaxf(f * mxv[i], f * mnv[i]), 0.f));
          }
        }
        *(bf16x8*)&Ab[b][adst[i]] = h;
      }
    }
  };

  f32x4 acc[2][4];
#pragma unroll
  for (int m = 0; m < 2; ++m)
#pragma unroll
    for (int t = 0; t < 4; ++t) {
      f32x4 z = {0.f, 0.f, 0.f, 0.f};
      acc[m][t] = z;
    }

  auto compute = [&](int b) {
#pragma unroll
    for (int kk = 0; kk < 2; ++kk) {
      int chq = kk * 4 + lg;
      bf16x8 a[2], bt[4];
#pragma unroll
      for (int m = 0; m < 2; ++m) {
        int row = wr * 32 + m * 16 + lr;
        a[m] = *(const bf16x8*)&Ab[b][(row * 8 + (chq ^ (row & 7))) * 8];
      }
#pragma unroll
      for (int t = 0; t < 4; ++t) {
        int row = wc * 64 + t * 16 + lr;
        bt[t] = *(const bf16x8*)&Bb[b][(row * 8 + (chq ^ (row & 7))) * 8];
      }
#pragma unroll
      for (int m = 0; m < 2; ++m)
#pragma unroll
        for (int t = 0; t < 4; ++t)
          acc[m][t] = __builtin_amdgcn_mfma_f32_16x16x32_bf16(
              a[m], bt[t], acc[m][t], 0, 0, 0);
    }
  };

  auto wait_cnt = [&](int n) {
    if (n >= 4)
      asm volatile("s_waitcnt vmcnt(4) lgkmcnt(0)" ::: "memory");
    else if (n >= 2)
      asm volatile("s_waitcnt vmcnt(2) lgkmcnt(0)" ::: "memory");
    else
      asm volatile("s_waitcnt vmcnt(0) lgkmcnt(0)" ::: "memory");
  };

  stage_regload(0); stage_gld(0, 0); stage_write(0, 0);
  stage_regload(1); stage_gld(1, 1); stage_write(1, 1);

  for (int t = 0; t < 22; ++t) {
    int b = t & 1;
    wait_cnt(gcnt(t + 1));                      // buf t ready; t+1 in flight
    __builtin_amdgcn_s_barrier();
    __builtin_amdgcn_sched_barrier(0);
    if (t + 2 <= 21) stage_regload(t + 2);
    compute(b);
    __builtin_amdgcn_s_barrier();
    __builtin_amdgcn_sched_barrier(0);
    if (t + 2 <= 21) {
      stage_gld(t + 2, b);
      stage_write(t + 2, b);
    }
  }
  asm volatile("s_waitcnt vmcnt(0) lgkmcnt(0)" ::: "memory");

#pragma unroll
  for (int m = 0; m < 2; ++m) {
    int rb = r0 + wr * 32 + m * 16 + lg * 4;    // C/D: col=lane&15, row=lg*4+reg
#pragma unroll
    for (int t = 0; t < 4; ++t) {
      int c = wc * 64 + t * 16 + lr;
      float bbias = bias[c];
#pragma unroll
      for (int r = 0; r < 4; ++r) {
        int rr = rb + r;
        if (rr < Nloc) out[(size_t)rr * 128 + c] = fmaxf(acc[m][t][r] + bbias, 0.f);
      }
    }
  }
}

extern "C" void kernel_launch(void* const* d_in, const int* in_sizes, int n_in,
                              void* d_out, int out_size, void* d_ws,
                              size_t ws_size, hipStream_t stream) {
  const float* x_i  = (const float*)d_in[0];
  const float* x_m  = (const float*)d_in[1];
  const int*   ei   = (const int*)d_in[2];
  const float* Wi_i = (const float*)d_in[3];
  const float* bi_i = (const float*)d_in[4];
  const float* Wi_m = (const float*)d_in[5];
  const float* bi_m = (const float*)d_in[6];
  const float* Wsc  = (const float*)d_in[7];
  const float* bsc  = (const float*)d_in[8];
  const float* Wo_i = (const float*)d_in[9];
  const float* bo_i = (const float*)d_in[10];
  const float* Wo_m = (const float*)d_in[11];
  const float* bo_m = (const float*)d_in[12];
  float* out = (float*)d_out;

  int Ni = in_sizes[0] / 128, Nm = in_sizes[1] / 128, E = in_sizes[2] / 2;
  const int* es = ei;
  const int* ee = ei + E;
  int nbi = (Ni + 255) / 256, nbm = (Nm + 255) / 256;   // <= 1024 assumed

  char* p = (char*)d_ws;
  auto alloc = [&](size_t bytes) {
    char* q = p;
    p += (bytes + 255) & ~(size_t)255;
    return q;
  };
  unsigned short* xp_i = (unsigned short*)alloc((size_t)Ni * 256 * 2);
  unsigned short* xp_m = (unsigned short*)alloc((size_t)Nm * 256 * 2);
  // contiguous zero-init group: a_i | a_m | deg_i | deg_m (one memset)
  float* a_i   = (float*)alloc((size_t)Ni * 4);
  float* a_m   = (float*)alloc((size_t)Nm * 4);
  int* deg_i   = (int*)alloc((size_t)Ni * 4);
  int* deg_m   = (int*)alloc((size_t)Nm * 4);
  char* zero_end = p;
  int* rp_i    = (int*)alloc((size_t)(Ni + 1) * 4);
  int* rp_m    = (int*)alloc((size_t)(Nm + 1) * 4);
  int* cur_i   = (int*)alloc((size_t)Ni * 4);
  int* cur_m   = (int*)alloc((size_t)Nm * 4);
  int* bs_i    = (int*)alloc((size_t)nbi * 4);
  int* bs_m    = (int*)alloc((size_t)nbm * 4);
  int* bb_i    = (int*)alloc((size_t)nbi * 4);
  int* bb_m    = (int*)alloc((size_t)nbm * 4);
  int* col_i   = (int*)alloc((size_t)E * 4);
  int* col_m   = (int*)alloc((size_t)E * 4);
  unsigned short* Wt_i = (unsigned short*)alloc((size_t)128 * 1408 * 2);
  unsigned short* Wt_m = (unsigned short*)alloc((size_t)128 * 1408 * 2);
  unsigned short* Wint_i = (unsigned short*)alloc((size_t)256 * 128 * 2);
  unsigned short* Wint_m = (unsigned short*)alloc((size_t)256 * 128 * 2);

  size_t used = (size_t)(p - (char*)d_ws);
  if (used + 256 > ws_size) return;
  size_t avail = ws_size - used - 256;
  long long srows_ll = (long long)(avail / 1040);
  int maxN = (Ni > Nm ? Ni : Nm);
  int maxPad = (maxN + 127) & ~127;
  int S = (int)(srows_ll > maxPad ? maxPad : srows_ll);
  S &= ~127;
  if (S < 128) return;
  unsigned short* Hg = (unsigned short*)alloc((size_t)S * 512 * 2);
  float4* scal = (float4*)alloc((size_t)S * 16);

  // one memset for a_i|a_m|deg_i|deg_m (padding zeroed too -- harmless)
  hipMemsetAsync(a_i, 0, (size_t)(zero_end - (char*)a_i), stream);

  k_prep_all<<<2 * 704 + 2 * 128, 256, 0, stream>>>(
      Wo_i, Wt_i, Wo_m, Wt_m, Wi_i, Wint_i, Wi_m, Wint_m);

  int nblk_i = (Ni + 63) / 64, nblk_m = (Nm + 63) / 64;
  k_gemm_in<<<nblk_i + nblk_m, 256, 0, stream>>>(
      x_i, Wint_i, bi_i, xp_i, a_i, Ni, nblk_i,
      x_m, Wint_m, bi_m, xp_m, a_m, Nm, Wsc);

  k_deg<<<(E + 255) / 256, 256, 0, stream>>>(es, ee, E, deg_i, deg_m);
  k_scan_blk<<<nbi + nbm, 256, 0, stream>>>(deg_i, bs_i, Ni, nbi,
                                            deg_m, bs_m, Nm);
  k_scan_top<<<2, 1024, 0, stream>>>(bs_i, bb_i, nbi, bs_m, bb_m, nbm);
  k_scan_wr<<<nbi + nbm, 256, 0, stream>>>(deg_i, bb_i, rp_i, cur_i, Ni, nbi,
                                           deg_m, bb_m, rp_m, cur_m, Nm, E);
  k_fill<<<(E + 255) / 256, 256, 0, stream>>>(es, ee, E, cur_i, col_i,
                                              cur_m, col_m);

  // intt side: own halves first in pooled blocks (OWN_FIRST=1)
  for (int base = 0; base < Ni; base += S) {
    int cnt = Ni - base; if (cnt > S) cnt = S;
    k_agg<<<(cnt + 3) / 4, 256, 0, stream>>>(xp_m, a_i, a_m, bsc, rp_i, col_i,
                                             Hg, scal, base, cnt);
    k_gemm_out<1><<<(cnt + 127) / 128, 512, 0, stream>>>(
        x_i + (size_t)base * 128, xp_i + (size_t)base * 256, Hg, scal,
        Wt_i, bo_i, out + (size_t)base * 128, cnt);
  }
  // mvtx side: gathered halves first (OWN_FIRST=0)
  float* out_m = out + (size_t)Ni * 128;
  for (int base = 0; base < Nm; base += S) {
    int cnt = Nm - base; if (cnt > S) cnt = S;
    k_agg<<<(cnt + 3) / 4, 256, 0, stream>>>(xp_i, a_m, a_i, bsc, rp_m, col_m,
                                             Hg, scal, base, cnt);
    k_gemm_out<0><<<(cnt + 127) / 128, 512, 0, stream>>>(
        x_m + (size_t)base * 128, xp_m + (size_t)base * 256, Hg, scal,
        Wt_m, bo_m, out_m + (size_t)base * 128, cnt);
  }
}